// Round 8
// baseline (249.438 us; speedup 1.0000x reference)
//
#include <hip/hip_runtime.h>
#include <math.h>

#define DM 512
#define NH 8
#define DH 64
#define SEQ 512
#define BATCH 8
#define MR 1023
#define PE_OFF 4489

typedef float4 f4;
typedef __attribute__((ext_vector_type(8))) short bf16x8;
typedef __attribute__((ext_vector_type(4))) float f32x4;
typedef __attribute__((ext_vector_type(8))) unsigned short u16x8;
typedef __attribute__((ext_vector_type(4))) unsigned short u16x4;

__device__ __forceinline__ unsigned short f2bf(float f) {
    unsigned x = __float_as_uint(f);
    unsigned r = x + 0x7fffu + ((x >> 16) & 1u);
    return (unsigned short)(r >> 16);
}
__device__ __forceinline__ float bf2f(unsigned short h) {
    return __uint_as_float(((unsigned)h) << 16);
}
__device__ __forceinline__ f32x4 mfma16(bf16x8 a, bf16x8 b, f32x4 c) {
    return __builtin_amdgcn_mfma_f32_16x16x32_bf16(a, b, c, 0, 0, 0);
}

// ---------------------------------------------------------------------------
// fp32 -> (bf16 hi, bf16 lo) split conversion
// ---------------------------------------------------------------------------
__device__ __forceinline__ void cvt8(const float* __restrict__ src,
                                     unsigned short* __restrict__ hi,
                                     unsigned short* __restrict__ lo, int i) {
    f4 a = *(const f4*)&src[i];
    f4 b = *(const f4*)&src[i + 4];
    float v[8] = {a.x, a.y, a.z, a.w, b.x, b.y, b.z, b.w};
    u16x8 h, l;
#pragma unroll
    for (int j = 0; j < 8; ++j) {
        unsigned short hb = f2bf(v[j]);
        h[j] = hb;
        l[j] = f2bf(v[j] - bf2f(hb));
    }
    *(u16x8*)&hi[i] = h;
    *(u16x8*)&lo[i] = l;
}

__global__ __launch_bounds__(256) void cvt_kernel(const float* __restrict__ src,
    unsigned short* __restrict__ hi, unsigned short* __restrict__ lo, int n)
{
    const int i = (blockIdx.x * 256 + threadIdx.x) * 8;
    if (i >= n) return;
    cvt8(src, hi, lo, i);
}

__global__ __launch_bounds__(256) void cvt_w_kernel(
    const float* __restrict__ w0, const float* __restrict__ w1,
    const float* __restrict__ w2, const float* __restrict__ w3,
    const float* __restrict__ w4, unsigned short* __restrict__ wb)
{
    const float* src = (blockIdx.y == 0) ? w0 : (blockIdx.y == 1) ? w1 :
                       (blockIdx.y == 2) ? w2 : (blockIdx.y == 3) ? w3 : w4;
    unsigned short* hi = wb + (size_t)blockIdx.y * 524288;
    unsigned short* lo = hi + 262144;
    const int i = (blockIdx.x * 256 + threadIdx.x) * 8;
    cvt8(src, hi, lo, i);
}

// ---------------------------------------------------------------------------
// Shared split-bf16 GEMM core: 64x64 tile, acc[2][2] of 16x16 frags per wave.
// ---------------------------------------------------------------------------
__device__ __forceinline__ void gemm_core(
    const unsigned short* __restrict__ Ah, const unsigned short* __restrict__ Al,
    const unsigned short* __restrict__ Wh, const unsigned short* __restrict__ Wl,
    int m0, int n0, f32x4 acc[2][2],
    unsigned short* LAh, unsigned short* LAl,
    unsigned short* LBh, unsigned short* LBl)
{
    const int tid = threadIdx.x;
    const int lane = tid & 63, wid = tid >> 6;
    const int wm = (wid >> 1) << 5, wn = (wid & 1) << 5;
    const int sr = tid >> 2, sc = (tid & 3) << 3;
    const int fr = lane & 15, g = lane >> 4;

#pragma unroll
    for (int i = 0; i < 2; ++i)
#pragma unroll
        for (int j = 0; j < 2; ++j)
            acc[i][j] = (f32x4){0.f, 0.f, 0.f, 0.f};

    const size_t arow = (size_t)(m0 + sr) * DM + sc;
    const size_t wrow = (size_t)(n0 + sr) * DM + sc;

    for (int k0 = 0; k0 < DM; k0 += 32) {
        u16x8 va_h = *(const u16x8*)&Ah[arow + k0];
        u16x8 va_l = *(const u16x8*)&Al[arow + k0];
        u16x8 vb_h = *(const u16x8*)&Wh[wrow + k0];
        u16x8 vb_l = *(const u16x8*)&Wl[wrow + k0];
        if (k0) __syncthreads();
        *(u16x8*)&LAh[sr * 40 + sc] = va_h;
        *(u16x8*)&LAl[sr * 40 + sc] = va_l;
        *(u16x8*)&LBh[sr * 40 + sc] = vb_h;
        *(u16x8*)&LBl[sr * 40 + sc] = vb_l;
        __syncthreads();

        bf16x8 a_h[2], a_l[2], b_h[2], b_l[2];
#pragma unroll
        for (int mi = 0; mi < 2; ++mi) {
            a_h[mi] = *(const bf16x8*)&LAh[(wm + (mi << 4) + fr) * 40 + (g << 3)];
            a_l[mi] = *(const bf16x8*)&LAl[(wm + (mi << 4) + fr) * 40 + (g << 3)];
        }
#pragma unroll
        for (int ni = 0; ni < 2; ++ni) {
            b_h[ni] = *(const bf16x8*)&LBh[(wn + (ni << 4) + fr) * 40 + (g << 3)];
            b_l[ni] = *(const bf16x8*)&LBl[(wn + (ni << 4) + fr) * 40 + (g << 3)];
        }
#pragma unroll
        for (int mi = 0; mi < 2; ++mi)
#pragma unroll
            for (int ni = 0; ni < 2; ++ni) {
                acc[mi][ni] = mfma16(a_h[mi], b_h[ni], acc[mi][ni]);
                acc[mi][ni] = mfma16(a_h[mi], b_l[ni], acc[mi][ni]);
                acc[mi][ni] = mfma16(a_l[mi], b_h[ni], acc[mi][ni]);
            }
    }
}

// ---------------------------------------------------------------------------
// Fused QKV projection. grid (24, 64): wsel = bx>>3 in {q,k,v}.
// q,k -> hi/lo [B,H,S,dh]; v -> hi/lo TRANSPOSED [B,H,dh,S].
// ---------------------------------------------------------------------------
__global__ __launch_bounds__(256) void qkv_kernel(
    const unsigned short* __restrict__ xh, const unsigned short* __restrict__ xl,
    const unsigned short* __restrict__ wb,
    const float* __restrict__ bq, const float* __restrict__ bk,
    const float* __restrict__ bv, const float* __restrict__ u,
    unsigned short* __restrict__ qh, unsigned short* __restrict__ ql,
    unsigned short* __restrict__ kh, unsigned short* __restrict__ kl,
    unsigned short* __restrict__ vth, unsigned short* __restrict__ vtl)
{
    __shared__ unsigned short LAh[64 * 40], LAl[64 * 40], LBh[64 * 40], LBl[64 * 40];
    const int wsel = blockIdx.x >> 3;
    const int n0 = (blockIdx.x & 7) << 6, m0 = blockIdx.y << 6;
    const unsigned short* Wh = wb + (size_t)wsel * 524288;
    const unsigned short* Wl = Wh + 262144;
    f32x4 acc[2][2];
    gemm_core(xh, xl, Wh, Wl, m0, n0, acc, LAh, LAl, LBh, LBl);

    const int tid = threadIdx.x, lane = tid & 63, wid = tid >> 6;
    const int wm = (wid >> 1) << 5, wn = (wid & 1) << 5;
    const int fr = lane & 15, g = lane >> 4;
    const float* bias = (wsel == 0) ? bq : (wsel == 1) ? bk : bv;

    if (wsel < 2) {
        unsigned short* oh = (wsel == 0) ? qh : kh;
        unsigned short* ol = (wsel == 0) ? ql : kl;
#pragma unroll
        for (int ni = 0; ni < 2; ++ni) {
            const int n_g = n0 + wn + (ni << 4) + fr;
            float bvv = bias[n_g] + ((wsel == 0) ? u[n_g] : 0.f);
            const int h = n_g >> 6, d = n_g & 63;
#pragma unroll
            for (int mi = 0; mi < 2; ++mi)
#pragma unroll
                for (int r = 0; r < 4; ++r) {
                    const int m_g = m0 + wm + (mi << 4) + (g << 2) + r;
                    const int b = m_g >> 9, s = m_g & 511;
                    const float val = acc[mi][ni][r] + bvv;
                    const size_t o = ((size_t)(b * NH + h) * SEQ + s) * DH + d;
                    const unsigned short hb = f2bf(val);
                    oh[o] = hb;
                    ol[o] = f2bf(val - bf2f(hb));
                }
        }
    } else {
#pragma unroll
        for (int ni = 0; ni < 2; ++ni) {
            const int n_g = n0 + wn + (ni << 4) + fr;
            const float bvv = bias[n_g];
            const int h = n_g >> 6, d = n_g & 63;
#pragma unroll
            for (int mi = 0; mi < 2; ++mi) {
                const int m_b = m0 + wm + (mi << 4) + (g << 2);
                const int b = m_b >> 9, s = m_b & 511;
                u16x4 hv, lv;
#pragma unroll
                for (int r = 0; r < 4; ++r) {
                    const float val = acc[mi][ni][r] + bvv;
                    hv[r] = f2bf(val);
                    lv[r] = f2bf(val - bf2f(hv[r]));
                }
                const size_t o = ((size_t)(b * NH + h) * DH + d) * SEQ + s;
                *(u16x4*)&vth[o] = hv;
                *(u16x4*)&vtl[o] = lv;
            }
        }
    }
}

// Rm[h][dd][d] hi/lo, dd in [0,1024)
__global__ __launch_bounds__(256) void rm_kernel(
    const unsigned short* __restrict__ peh, const unsigned short* __restrict__ pel,
    const unsigned short* __restrict__ wrh, const unsigned short* __restrict__ wrl,
    unsigned short* __restrict__ rmh, unsigned short* __restrict__ rml)
{
    __shared__ unsigned short LAh[64 * 40], LAl[64 * 40], LBh[64 * 40], LBl[64 * 40];
    const int n0 = blockIdx.x << 6, m0 = blockIdx.y << 6;
    f32x4 acc[2][2];
    gemm_core(peh, pel, wrh, wrl, m0, n0, acc, LAh, LAl, LBh, LBl);

    const int tid = threadIdx.x, lane = tid & 63, wid = tid >> 6;
    const int wm = (wid >> 1) << 5, wn = (wid & 1) << 5;
    const int fr = lane & 15, g = lane >> 4;
#pragma unroll
    for (int ni = 0; ni < 2; ++ni) {
        const int n_g = n0 + wn + (ni << 4) + fr;
        const int h = n_g >> 6, d = n_g & 63;
#pragma unroll
        for (int mi = 0; mi < 2; ++mi)
#pragma unroll
            for (int r = 0; r < 4; ++r) {
                const int dd = m0 + wm + (mi << 4) + (g << 2) + r;
                const float val = acc[mi][ni][r];
                const size_t o = (((size_t)h << 10) + dd) * DH + d;
                const unsigned short hb = f2bf(val);
                rmh[o] = hb;
                rml[o] = f2bf(val - bf2f(hb));
            }
    }
}

// out = ctx @ wo^T + bo  (f32 out)
__global__ __launch_bounds__(256) void out_kernel(
    const unsigned short* __restrict__ cth, const unsigned short* __restrict__ ctl,
    const unsigned short* __restrict__ woh, const unsigned short* __restrict__ wol,
    const float* __restrict__ bo, float* __restrict__ out)
{
    __shared__ unsigned short LAh[64 * 40], LAl[64 * 40], LBh[64 * 40], LBl[64 * 40];
    const int n0 = blockIdx.x << 6, m0 = blockIdx.y << 6;
    f32x4 acc[2][2];
    gemm_core(cth, ctl, woh, wol, m0, n0, acc, LAh, LAl, LBh, LBl);

    const int tid = threadIdx.x, lane = tid & 63, wid = tid >> 6;
    const int wm = (wid >> 1) << 5, wn = (wid & 1) << 5;
    const int fr = lane & 15, g = lane >> 4;
#pragma unroll
    for (int ni = 0; ni < 2; ++ni) {
        const int n_g = n0 + wn + (ni << 4) + fr;
        const float bvv = bo[n_g];
#pragma unroll
        for (int mi = 0; mi < 2; ++mi)
#pragma unroll
            for (int r = 0; r < 4; ++r) {
                const int m_g = m0 + wm + (mi << 4) + (g << 2) + r;
                out[(size_t)m_g * DM + n_g] = acc[mi][ni][r] + bvv;
            }
    }
}

// rcorr[h][dd] = sum_d (v_bias - u) * Rm
__global__ __launch_bounds__(64) void corr_kernel(
    const unsigned short* __restrict__ rmh, const unsigned short* __restrict__ rml,
    const float* __restrict__ u, const float* __restrict__ vb,
    float* __restrict__ rc)
{
    const int h = blockIdx.y;
    const int dd = (blockIdx.x << 6) + threadIdx.x;
    float s = 0.f;
    if (dd < MR) {
        const size_t ro = (((size_t)h << 10) + dd) * DH;
        const float* uu = u + h * DH;
        const float* vv = vb + h * DH;
        for (int d = 0; d < DH; ++d)
            s = fmaf(vv[d] - uu[d], bf2f(rmh[ro + d]) + bf2f(rml[ro + d]), s);
    }
    rc[((size_t)h << 10) + dd] = s;
}

// ---------------------------------------------------------------------------
// MFMA flash attention (R3 structure + fixes). Block = (i-tile 64, j-half,
// b*8+h): 4 waves x 16 rows, 4 j-tiles of 64 per block. K staged in LDS with
// async prefetch (T14: next tile's loads issued before compute); V and rm
// read direct from L2. Partials (O, m, l) written f32; merge_kernel combines
// the two j-halves.
// ---------------------------------------------------------------------------
__global__ __launch_bounds__(256, 3) void attn_kernel(
    const unsigned short* __restrict__ qh_g, const unsigned short* __restrict__ ql_g,
    const unsigned short* __restrict__ kh_g, const unsigned short* __restrict__ kl_g,
    const unsigned short* __restrict__ vh_g, const unsigned short* __restrict__ vl_g,
    const unsigned short* __restrict__ rmh, const unsigned short* __restrict__ rml,
    const float* __restrict__ rc,
    float* __restrict__ Op, float* __restrict__ Mp, float* __restrict__ Lp)
{
    __shared__ unsigned short Kh[64][72], Kl[64][72];
    __shared__ unsigned short Pdd[4][16][84];   // wave-private bf16(pos+rc)
    __shared__ unsigned short Pth[4][16][72];   // wave-private P hi
    __shared__ unsigned short Ptl[4][16][72];   // wave-private P lo

    const int tid = threadIdx.x;
    const int lane = tid & 63, wid = tid >> 6;
    const int g = lane >> 4, c = lane & 15;
    const int i0 = blockIdx.x << 6;
    const int jh = blockIdx.y;
    const int bhid = blockIdx.z;
    const int h = bhid & 7;
    const int R0 = i0 + (wid << 4);
    const size_t bh = (size_t)bhid * (SEQ * DH);
    const int jbase = jh << 8;

    // K staging map: thread covers rows {srow, srow+32} x 16B chunk sch
    const int srow = tid >> 3;
    const int sch = (tid & 7) << 3;

    // Q fragments hoisted (rows R0..R0+15)
    bf16x8 qhf[2], qlf[2];
#pragma unroll
    for (int ks = 0; ks < 2; ++ks) {
        const size_t qo = bh + (size_t)(R0 + c) * DH + (ks << 5) + (g << 3);
        qhf[ks] = *(const bf16x8*)&qh_g[qo];
        qlf[ks] = *(const bf16x8*)&ql_g[qo];
    }

    f32x4 Oacc[4];
#pragma unroll
    for (int nf = 0; nf < 4; ++nf) Oacc[nf] = (f32x4){0.f, 0.f, 0.f, 0.f};
    float m_r[4] = {-3e38f, -3e38f, -3e38f, -3e38f};
    float l_r[4] = {0.f, 0.f, 0.f, 0.f};

    const float* rch = rc + (h << 10);
    const unsigned short* rmhh = rmh + ((size_t)h << 16);
    const unsigned short* rmlh = rml + ((size_t)h << 16);

    // prologue: prefetch tile 0's K hi/lo into registers
    u16x8 pk0, pk1, pk2, pk3;
    {
        const size_t base = bh + (size_t)(jbase + srow) * DH + sch;
        pk0 = *(const u16x8*)&kh_g[base];
        pk1 = *(const u16x8*)&kh_g[base + 32 * DH];
        pk2 = *(const u16x8*)&kl_g[base];
        pk3 = *(const u16x8*)&kl_g[base + 32 * DH];
    }

#pragma unroll
    for (int t = 0; t < 4; ++t) {
        const int j0 = jbase + (t << 6);
        __syncthreads();                     // K-buf free
        *(u16x8*)&Kh[srow][sch] = pk0;
        *(u16x8*)&Kh[srow + 32][sch] = pk1;
        *(u16x8*)&Kl[srow][sch] = pk2;
        *(u16x8*)&Kl[srow + 32][sch] = pk3;
        __syncthreads();                     // K-buf ready
        if (t < 3) {                         // T14: issue next tile's loads now
            const size_t nbase = bh + (size_t)(j0 + 64 + srow) * DH + sch;
            pk0 = *(const u16x8*)&kh_g[nbase];
            pk1 = *(const u16x8*)&kh_g[nbase + 32 * DH];
            pk2 = *(const u16x8*)&kl_g[nbase];
            pk3 = *(const u16x8*)&kl_g[nbase + 32 * DH];
        }

        // content scores from LDS K
        __builtin_amdgcn_s_setprio(1);
        f32x4 accs[4];
#pragma unroll
        for (int nf = 0; nf < 4; ++nf) accs[nf] = (f32x4){0.f, 0.f, 0.f, 0.f};
#pragma unroll
        for (int ks = 0; ks < 2; ++ks)
#pragma unroll
            for (int nf = 0; nf < 4; ++nf) {
                bf16x8 b_h = *(const bf16x8*)&Kh[(nf << 4) + c][(ks << 5) + (g << 3)];
                bf16x8 b_l = *(const bf16x8*)&Kl[(nf << 4) + c][(ks << 5) + (g << 3)];
                accs[nf] = mfma16(qhf[ks], b_h, accs[nf]);
                accs[nf] = mfma16(qhf[ks], b_l, accs[nf]);
                accs[nf] = mfma16(qlf[ks], b_h, accs[nf]);
            }

        // position dd-GEMM, rm direct from global (L2-resident)
        const int base_g = j0 - R0 + 496;
#pragma unroll
        for (int f = 0; f < 5; ++f) {
            f32x4 ap = (f32x4){0.f, 0.f, 0.f, 0.f};
#pragma unroll
            for (int ks = 0; ks < 2; ++ks) {
                const size_t ro = (size_t)(base_g + (f << 4) + c) * DH
                                + (ks << 5) + (g << 3);
                bf16x8 b_h = *(const bf16x8*)&rmhh[ro];
                bf16x8 b_l = *(const bf16x8*)&rmlh[ro];
                ap = mfma16(qhf[ks], b_h, ap);
                ap = mfma16(qhf[ks], b_l, ap);
                ap = mfma16(qlf[ks], b_h, ap);
            }
            const float rcv = rch[base_g + (f << 4) + c];
#pragma unroll
            for (int r = 0; r < 4; ++r)
                Pdd[wid][(g << 2) + r][(f << 4) + c] = f2bf(ap[r] + rcv);
        }
        __builtin_amdgcn_s_setprio(0);

        // online softmax per row (gather Pdd at ddl = j - i + 15)
#pragma unroll
        for (int r = 0; r < 4; ++r) {
            const int irow = (g << 2) + r;
            float sc[4];
#pragma unroll
            for (int nf = 0; nf < 4; ++nf) {
                const int ddl = (nf << 4) + c - irow + 15;
                sc[nf] = (accs[nf][r] + bf2f(Pdd[wid][irow][ddl])) * 0.125f;
            }
            float mt = fmaxf(fmaxf(sc[0], sc[1]), fmaxf(sc[2], sc[3]));
#pragma unroll
            for (int off = 8; off; off >>= 1) mt = fmaxf(mt, __shfl_xor(mt, off, 16));
            const float mn = fmaxf(m_r[r], mt);
            const float alpha = __expf(m_r[r] - mn);
            m_r[r] = mn;
            float rs = 0.f;
#pragma unroll
            for (int nf = 0; nf < 4; ++nf) {
                const float pp = __expf(sc[nf] - mn);
                const unsigned short hb = f2bf(pp);
                Pth[wid][irow][(nf << 4) + c] = hb;
                Ptl[wid][irow][(nf << 4) + c] = f2bf(pp - bf2f(hb));
                rs += pp;
            }
#pragma unroll
            for (int off = 8; off; off >>= 1) rs += __shfl_xor(rs, off, 16);
            l_r[r] = l_r[r] * alpha + rs;
#pragma unroll
            for (int nf = 0; nf < 4; ++nf) Oacc[nf][r] *= alpha;
        }

        // PV: A = P hi/lo from LDS, B = Vt hi/lo direct global (L2)
        __builtin_amdgcn_s_setprio(1);
#pragma unroll
        for (int ks = 0; ks < 2; ++ks) {
            bf16x8 ph = *(const bf16x8*)&Pth[wid][c][(ks << 5) + (g << 3)];
            bf16x8 pl = *(const bf16x8*)&Ptl[wid][c][(ks << 5) + (g << 3)];
#pragma unroll
            for (int nf = 0; nf < 4; ++nf) {
                const size_t vo = bh + (size_t)((nf << 4) + c) * SEQ + j0
                                + (ks << 5) + (g << 3);
                bf16x8 v_h = *(const bf16x8*)&vh_g[vo];
                bf16x8 v_l = *(const bf16x8*)&vl_g[vo];
                Oacc[nf] = mfma16(ph, v_h, Oacc[nf]);
                Oacc[nf] = mfma16(ph, v_l, Oacc[nf]);
                Oacc[nf] = mfma16(pl, v_h, Oacc[nf]);
            }
        }
        __builtin_amdgcn_s_setprio(0);
    }

    // epilogue: write f32 partials (per j-half)
    const size_t prow = (size_t)jh * 32768 + (size_t)bhid * 512;
#pragma unroll
    for (int nf = 0; nf < 4; ++nf)
#pragma unroll
        for (int r = 0; r < 4; ++r) {
            const int s = R0 + (g << 2) + r;
            Op[(prow + s) * 64 + (nf << 4) + c] = Oacc[nf][r];
        }
    if (c == 0) {
#pragma unroll
        for (int r = 0; r < 4; ++r) {
            const int s = R0 + (g << 2) + r;
            Mp[prow + s] = m_r[r];
            Lp[prow + s] = l_r[r];
        }
    }
}

// 2-way flash combine of the j-half partials -> ctx bf16 hi/lo
__global__ __launch_bounds__(256) void merge_kernel(
    const float* __restrict__ Op, const float* __restrict__ Mp,
    const float* __restrict__ Lp,
    unsigned short* __restrict__ cth, unsigned short* __restrict__ ctl)
{
    const int idx = blockIdx.x * 256 + threadIdx.x;   // B*H*S*16
    const int d4 = (idx & 15) << 2;
    const int rowid = idx >> 4;                        // bhid*512 + s
    const int bhid = rowid >> 9, s = rowid & 511;
    const int b = bhid >> 3, h = bhid & 7;

    const float m0 = Mp[rowid], m1 = Mp[32768 + rowid];
    const float l0 = Lp[rowid], l1 = Lp[32768 + rowid];
    const float M = fmaxf(m0, m1);
    const float s0 = __expf(m0 - M), s1 = __expf(m1 - M);
    const float inv = 1.f / (l0 * s0 + l1 * s1);
    const f4 o0 = *(const f4*)&Op[((size_t)rowid << 6) + d4];
    const f4 o1 = *(const f4*)&Op[((size_t)(32768 + rowid) << 6) + d4];
    float vals[4] = {
        (o0.x * s0 + o1.x * s1) * inv, (o0.y * s0 + o1.y * s1) * inv,
        (o0.z * s0 + o1.z * s1) * inv, (o0.w * s0 + o1.w * s1) * inv};
    u16x4 hv, lv;
#pragma unroll
    for (int e = 0; e < 4; ++e) {
        hv[e] = f2bf(vals[e]);
        lv[e] = f2bf(vals[e] - bf2f(hv[e]));
    }
    const size_t o = ((size_t)b * SEQ + s) * DM + (h << 6) + d4;
    *(u16x4*)&cth[o] = hv;
    *(u16x4*)&ctl[o] = lv;
}

extern "C" void kernel_launch(void* const* d_in, const int* in_sizes, int n_in,
                              void* d_out, int out_size, void* d_ws, size_t ws_size,
                              hipStream_t stream)
{
    const float* x  = (const float*)d_in[0];
    const float* wq = (const float*)d_in[1];
    const float* bq = (const float*)d_in[2];
    const float* wk = (const float*)d_in[3];
    const float* bk = (const float*)d_in[4];
    const float* wv = (const float*)d_in[5];
    const float* bv = (const float*)d_in[6];
    const float* wo = (const float*)d_in[7];
    const float* bo = (const float*)d_in[8];
    const float* wr = (const float*)d_in[9];
    const float* u  = (const float*)d_in[10];
    const float* vb = (const float*)d_in[11];
    const float* pe = (const float*)d_in[12];
    float* out = (float*)d_out;
    unsigned short* us = (unsigned short*)d_ws;

    unsigned short* xh  = us;                    // 2097152
    unsigned short* xl  = us + 2097152;
    unsigned short* wb  = us + 4194304;          // 5 x (hi 262144 + lo 262144)
    unsigned short* peh = us + 6815744;          // 524288
    unsigned short* pel = us + 7340032;
    unsigned short* qh  = us + 7864320;          // 2097152 each
    unsigned short* ql  = us + 9961472;
    unsigned short* kh  = us + 12058624;
    unsigned short* kl  = us + 14155776;
    unsigned short* vth = us + 16252928;
    unsigned short* vtl = us + 18350080;
    unsigned short* rmh = us + 20447232;         // 524288 each
    unsigned short* rml = us + 20971520;
    unsigned short* cth = us + 21495808;
    unsigned short* ctl = us + 23592960;
    float* rc = (float*)(us + 25690112);         // 8192 f32
    float* Op = (float*)(us + 25706496);         // [2][64][512][64] f32
    float* Mp = Op + 4194304;                    // [2][64][512] f32
    float* Lp = Mp + 65536;

    unsigned short* woh = wb + 3 * 524288;
    unsigned short* wol = woh + 262144;
    unsigned short* wrh = wb + 4 * 524288;
    unsigned short* wrl = wrh + 262144;

    dim3 blk(256);
    cvt_kernel<<<1024, blk, 0, stream>>>(x, xh, xl, 2097152);
    cvt_w_kernel<<<dim3(128, 5), blk, 0, stream>>>(wq, wk, wv, wo, wr, wb);
    cvt_kernel<<<256, blk, 0, stream>>>(pe + (size_t)PE_OFF * DM, peh, pel, 523776);

    qkv_kernel<<<dim3(24, 64), blk, 0, stream>>>(xh, xl, wb, bq, bk, bv, u,
                                                 qh, ql, kh, kl, vth, vtl);
    rm_kernel<<<dim3(8, 16), blk, 0, stream>>>(peh, pel, wrh, wrl, rmh, rml);
    corr_kernel<<<dim3(16, 8), dim3(64), 0, stream>>>(rmh, rml, u, vb, rc);
    attn_kernel<<<dim3(8, 2, 64), blk, 0, stream>>>(qh, ql, kh, kl, vth, vtl,
                                                    rmh, rml, rc, Op, Mp, Lp);
    merge_kernel<<<2048, blk, 0, stream>>>(Op, Mp, Lp, cth, ctl);
    out_kernel<<<dim3(8, 64), blk, 0, stream>>>(cth, ctl, woh, wol, bo, out);
}

// Round 9
// 127.104 us; speedup vs baseline: 1.9625x; 1.9625x over previous
//
#include <hip/hip_runtime.h>
#include <math.h>

#define DM 512
#define NH 8
#define DH 64
#define SEQ 512
#define BATCH 8
#define MR 1023
#define PE_OFF 4489

typedef float4 f4;
typedef __attribute__((ext_vector_type(8))) short bf16x8;
typedef __attribute__((ext_vector_type(4))) float f32x4;
typedef __attribute__((ext_vector_type(8))) unsigned short u16x8;
typedef __attribute__((ext_vector_type(4))) unsigned short u16x4;

__device__ __forceinline__ unsigned short f2bf(float f) {
    unsigned x = __float_as_uint(f);
    unsigned r = x + 0x7fffu + ((x >> 16) & 1u);
    return (unsigned short)(r >> 16);
}
__device__ __forceinline__ float bf2f(unsigned short h) {
    return __uint_as_float(((unsigned)h) << 16);
}
__device__ __forceinline__ f32x4 mfma16(bf16x8 a, bf16x8 b, f32x4 c) {
    return __builtin_amdgcn_mfma_f32_16x16x32_bf16(a, b, c, 0, 0, 0);
}

// ---------------------------------------------------------------------------
// fp32 -> (bf16 hi, bf16 lo) split conversion
// ---------------------------------------------------------------------------
__device__ __forceinline__ void cvt8(const float* __restrict__ src,
                                     unsigned short* __restrict__ hi,
                                     unsigned short* __restrict__ lo, int i) {
    f4 a = *(const f4*)&src[i];
    f4 b = *(const f4*)&src[i + 4];
    float v[8] = {a.x, a.y, a.z, a.w, b.x, b.y, b.z, b.w};
    u16x8 h, l;
#pragma unroll
    for (int j = 0; j < 8; ++j) {
        unsigned short hb = f2bf(v[j]);
        h[j] = hb;
        l[j] = f2bf(v[j] - bf2f(hb));
    }
    *(u16x8*)&hi[i] = h;
    *(u16x8*)&lo[i] = l;
}

__global__ __launch_bounds__(256) void cvt_kernel(const float* __restrict__ src,
    unsigned short* __restrict__ hi, unsigned short* __restrict__ lo, int n)
{
    const int i = (blockIdx.x * 256 + threadIdx.x) * 8;
    if (i >= n) return;
    cvt8(src, hi, lo, i);
}

__global__ __launch_bounds__(256) void cvt_w_kernel(
    const float* __restrict__ w0, const float* __restrict__ w1,
    const float* __restrict__ w2, const float* __restrict__ w3,
    const float* __restrict__ w4, unsigned short* __restrict__ wb)
{
    const float* src = (blockIdx.y == 0) ? w0 : (blockIdx.y == 1) ? w1 :
                       (blockIdx.y == 2) ? w2 : (blockIdx.y == 3) ? w3 : w4;
    unsigned short* hi = wb + (size_t)blockIdx.y * 524288;
    unsigned short* lo = hi + 262144;
    const int i = (blockIdx.x * 256 + threadIdx.x) * 8;
    cvt8(src, hi, lo, i);
}

// ---------------------------------------------------------------------------
// Shared split-bf16 GEMM core: 64x64 tile, acc[2][2] of 16x16 frags per wave.
// ---------------------------------------------------------------------------
__device__ __forceinline__ void gemm_core(
    const unsigned short* __restrict__ Ah, const unsigned short* __restrict__ Al,
    const unsigned short* __restrict__ Wh, const unsigned short* __restrict__ Wl,
    int m0, int n0, f32x4 acc[2][2],
    unsigned short* LAh, unsigned short* LAl,
    unsigned short* LBh, unsigned short* LBl)
{
    const int tid = threadIdx.x;
    const int lane = tid & 63, wid = tid >> 6;
    const int wm = (wid >> 1) << 5, wn = (wid & 1) << 5;
    const int sr = tid >> 2, sc = (tid & 3) << 3;
    const int fr = lane & 15, g = lane >> 4;

#pragma unroll
    for (int i = 0; i < 2; ++i)
#pragma unroll
        for (int j = 0; j < 2; ++j)
            acc[i][j] = (f32x4){0.f, 0.f, 0.f, 0.f};

    const size_t arow = (size_t)(m0 + sr) * DM + sc;
    const size_t wrow = (size_t)(n0 + sr) * DM + sc;

    for (int k0 = 0; k0 < DM; k0 += 32) {
        u16x8 va_h = *(const u16x8*)&Ah[arow + k0];
        u16x8 va_l = *(const u16x8*)&Al[arow + k0];
        u16x8 vb_h = *(const u16x8*)&Wh[wrow + k0];
        u16x8 vb_l = *(const u16x8*)&Wl[wrow + k0];
        if (k0) __syncthreads();
        *(u16x8*)&LAh[sr * 40 + sc] = va_h;
        *(u16x8*)&LAl[sr * 40 + sc] = va_l;
        *(u16x8*)&LBh[sr * 40 + sc] = vb_h;
        *(u16x8*)&LBl[sr * 40 + sc] = vb_l;
        __syncthreads();

        bf16x8 a_h[2], a_l[2], b_h[2], b_l[2];
#pragma unroll
        for (int mi = 0; mi < 2; ++mi) {
            a_h[mi] = *(const bf16x8*)&LAh[(wm + (mi << 4) + fr) * 40 + (g << 3)];
            a_l[mi] = *(const bf16x8*)&LAl[(wm + (mi << 4) + fr) * 40 + (g << 3)];
        }
#pragma unroll
        for (int ni = 0; ni < 2; ++ni) {
            b_h[ni] = *(const bf16x8*)&LBh[(wn + (ni << 4) + fr) * 40 + (g << 3)];
            b_l[ni] = *(const bf16x8*)&LBl[(wn + (ni << 4) + fr) * 40 + (g << 3)];
        }
#pragma unroll
        for (int mi = 0; mi < 2; ++mi)
#pragma unroll
            for (int ni = 0; ni < 2; ++ni) {
                acc[mi][ni] = mfma16(a_h[mi], b_h[ni], acc[mi][ni]);
                acc[mi][ni] = mfma16(a_h[mi], b_l[ni], acc[mi][ni]);
                acc[mi][ni] = mfma16(a_l[mi], b_h[ni], acc[mi][ni]);
            }
    }
}

// ---------------------------------------------------------------------------
// Fused QKV projection. grid (24, 64): wsel = bx>>3 in {q,k,v}.
// q,k -> hi/lo [B,H,S,dh]; v -> hi/lo TRANSPOSED [B,H,dh,S].
// ---------------------------------------------------------------------------
__global__ __launch_bounds__(256) void qkv_kernel(
    const unsigned short* __restrict__ xh, const unsigned short* __restrict__ xl,
    const unsigned short* __restrict__ wb,
    const float* __restrict__ bq, const float* __restrict__ bk,
    const float* __restrict__ bv, const float* __restrict__ u,
    unsigned short* __restrict__ qh, unsigned short* __restrict__ ql,
    unsigned short* __restrict__ kh, unsigned short* __restrict__ kl,
    unsigned short* __restrict__ vth, unsigned short* __restrict__ vtl)
{
    __shared__ unsigned short LAh[64 * 40], LAl[64 * 40], LBh[64 * 40], LBl[64 * 40];
    const int wsel = blockIdx.x >> 3;
    const int n0 = (blockIdx.x & 7) << 6, m0 = blockIdx.y << 6;
    const unsigned short* Wh = wb + (size_t)wsel * 524288;
    const unsigned short* Wl = Wh + 262144;
    f32x4 acc[2][2];
    gemm_core(xh, xl, Wh, Wl, m0, n0, acc, LAh, LAl, LBh, LBl);

    const int tid = threadIdx.x, lane = tid & 63, wid = tid >> 6;
    const int wm = (wid >> 1) << 5, wn = (wid & 1) << 5;
    const int fr = lane & 15, g = lane >> 4;
    const float* bias = (wsel == 0) ? bq : (wsel == 1) ? bk : bv;

    if (wsel < 2) {
        unsigned short* oh = (wsel == 0) ? qh : kh;
        unsigned short* ol = (wsel == 0) ? ql : kl;
#pragma unroll
        for (int ni = 0; ni < 2; ++ni) {
            const int n_g = n0 + wn + (ni << 4) + fr;
            float bvv = bias[n_g] + ((wsel == 0) ? u[n_g] : 0.f);
            const int h = n_g >> 6, d = n_g & 63;
#pragma unroll
            for (int mi = 0; mi < 2; ++mi)
#pragma unroll
                for (int r = 0; r < 4; ++r) {
                    const int m_g = m0 + wm + (mi << 4) + (g << 2) + r;
                    const int b = m_g >> 9, s = m_g & 511;
                    const float val = acc[mi][ni][r] + bvv;
                    const size_t o = ((size_t)(b * NH + h) * SEQ + s) * DH + d;
                    const unsigned short hb = f2bf(val);
                    oh[o] = hb;
                    ol[o] = f2bf(val - bf2f(hb));
                }
        }
    } else {
#pragma unroll
        for (int ni = 0; ni < 2; ++ni) {
            const int n_g = n0 + wn + (ni << 4) + fr;
            const float bvv = bias[n_g];
            const int h = n_g >> 6, d = n_g & 63;
#pragma unroll
            for (int mi = 0; mi < 2; ++mi) {
                const int m_b = m0 + wm + (mi << 4) + (g << 2);
                const int b = m_b >> 9, s = m_b & 511;
                u16x4 hv, lv;
#pragma unroll
                for (int r = 0; r < 4; ++r) {
                    const float val = acc[mi][ni][r] + bvv;
                    hv[r] = f2bf(val);
                    lv[r] = f2bf(val - bf2f(hv[r]));
                }
                const size_t o = ((size_t)(b * NH + h) * DH + d) * SEQ + s;
                *(u16x4*)&vth[o] = hv;
                *(u16x4*)&vtl[o] = lv;
            }
        }
    }
}

// Rm[h][dd][d] hi/lo, dd in [0,1024)
__global__ __launch_bounds__(256) void rm_kernel(
    const unsigned short* __restrict__ peh, const unsigned short* __restrict__ pel,
    const unsigned short* __restrict__ wrh, const unsigned short* __restrict__ wrl,
    unsigned short* __restrict__ rmh, unsigned short* __restrict__ rml)
{
    __shared__ unsigned short LAh[64 * 40], LAl[64 * 40], LBh[64 * 40], LBl[64 * 40];
    const int n0 = blockIdx.x << 6, m0 = blockIdx.y << 6;
    f32x4 acc[2][2];
    gemm_core(peh, pel, wrh, wrl, m0, n0, acc, LAh, LAl, LBh, LBl);

    const int tid = threadIdx.x, lane = tid & 63, wid = tid >> 6;
    const int wm = (wid >> 1) << 5, wn = (wid & 1) << 5;
    const int fr = lane & 15, g = lane >> 4;
#pragma unroll
    for (int ni = 0; ni < 2; ++ni) {
        const int n_g = n0 + wn + (ni << 4) + fr;
        const int h = n_g >> 6, d = n_g & 63;
#pragma unroll
        for (int mi = 0; mi < 2; ++mi)
#pragma unroll
            for (int r = 0; r < 4; ++r) {
                const int dd = m0 + wm + (mi << 4) + (g << 2) + r;
                const float val = acc[mi][ni][r];
                const size_t o = (((size_t)h << 10) + dd) * DH + d;
                const unsigned short hb = f2bf(val);
                rmh[o] = hb;
                rml[o] = f2bf(val - bf2f(hb));
            }
    }
}

// out = ctx @ wo^T + bo  (f32 out)
__global__ __launch_bounds__(256) void out_kernel(
    const unsigned short* __restrict__ cth, const unsigned short* __restrict__ ctl,
    const unsigned short* __restrict__ woh, const unsigned short* __restrict__ wol,
    const float* __restrict__ bo, float* __restrict__ out)
{
    __shared__ unsigned short LAh[64 * 40], LAl[64 * 40], LBh[64 * 40], LBl[64 * 40];
    const int n0 = blockIdx.x << 6, m0 = blockIdx.y << 6;
    f32x4 acc[2][2];
    gemm_core(cth, ctl, woh, wol, m0, n0, acc, LAh, LAl, LBh, LBl);

    const int tid = threadIdx.x, lane = tid & 63, wid = tid >> 6;
    const int wm = (wid >> 1) << 5, wn = (wid & 1) << 5;
    const int fr = lane & 15, g = lane >> 4;
#pragma unroll
    for (int ni = 0; ni < 2; ++ni) {
        const int n_g = n0 + wn + (ni << 4) + fr;
        const float bvv = bo[n_g];
#pragma unroll
        for (int mi = 0; mi < 2; ++mi)
#pragma unroll
            for (int r = 0; r < 4; ++r) {
                const int m_g = m0 + wm + (mi << 4) + (g << 2) + r;
                out[(size_t)m_g * DM + n_g] = acc[mi][ni][r] + bvv;
            }
    }
}

// rcorr[h][dd] = sum_d (v_bias - u) * Rm
__global__ __launch_bounds__(64) void corr_kernel(
    const unsigned short* __restrict__ rmh, const unsigned short* __restrict__ rml,
    const float* __restrict__ u, const float* __restrict__ vb,
    float* __restrict__ rc)
{
    const int h = blockIdx.y;
    const int dd = (blockIdx.x << 6) + threadIdx.x;
    float s = 0.f;
    if (dd < MR) {
        const size_t ro = (((size_t)h << 10) + dd) * DH;
        const float* uu = u + h * DH;
        const float* vv = vb + h * DH;
        for (int d = 0; d < DH; ++d)
            s = fmaf(vv[d] - uu[d], bf2f(rmh[ro + d]) + bf2f(rml[ro + d]), s);
    }
    rc[((size_t)h << 10) + dd] = s;
}

// ---------------------------------------------------------------------------
// MFMA flash attention — R3 structure (measured 90 us, logical-only HBM
// traffic) + T14 register prefetch of next K/V tile. Block = (i-tile 64, h,
// b), 4 waves x 16 rows, j-tiles of 64, K+V staged in LDS, grid 512.
// ---------------------------------------------------------------------------
__global__ __launch_bounds__(256) void attn_kernel(
    const unsigned short* __restrict__ qh_g, const unsigned short* __restrict__ ql_g,
    const unsigned short* __restrict__ kh_g, const unsigned short* __restrict__ kl_g,
    const unsigned short* __restrict__ vh_g, const unsigned short* __restrict__ vl_g,
    const unsigned short* __restrict__ rmh, const unsigned short* __restrict__ rml,
    const float* __restrict__ rc,
    unsigned short* __restrict__ cth, unsigned short* __restrict__ ctl)
{
    __shared__ unsigned short Kh[64][72], Kl[64][72], Vh[64][72], Vl[64][72];
    __shared__ unsigned short Pdd[4][16][84];   // wave-private, bf16(pos+rc)
    __shared__ float Pt[4][16][68];             // wave-private, P f32

    const int tid = threadIdx.x;
    const int lane = tid & 63, wid = tid >> 6;
    const int g = lane >> 4, c = lane & 15;
    const int i0 = blockIdx.x << 6;
    const int h = blockIdx.y, b = blockIdx.z;
    const int R0 = i0 + (wid << 4);
    const size_t bh = (size_t)(b * NH + h) * (SEQ * DH);

    // staging map: thread covers rows {srow, srow+32} x 16B chunk sch
    const int srow = tid >> 3;           // 0..31
    const int sch = (tid & 7) << 3;      // 0,8,...,56

    // Q fragments hoisted (rows R0..R0+15)
    bf16x8 qhf[2], qlf[2];
#pragma unroll
    for (int ks = 0; ks < 2; ++ks) {
        const size_t qo = bh + (size_t)(R0 + c) * DH + (ks << 5) + (g << 3);
        qhf[ks] = *(const bf16x8*)&qh_g[qo];
        qlf[ks] = *(const bf16x8*)&ql_g[qo];
    }

    f32x4 Oacc[4];
#pragma unroll
    for (int nf = 0; nf < 4; ++nf) Oacc[nf] = (f32x4){0.f, 0.f, 0.f, 0.f};
    float m_r[4] = {-3e38f, -3e38f, -3e38f, -3e38f};
    float l_r[4] = {0.f, 0.f, 0.f, 0.f};

    const float* rch = rc + (h << 10);
    const unsigned short* rmhh = rmh + ((size_t)h << 16);
    const unsigned short* rmlh = rml + ((size_t)h << 16);

    // T14 prefetch registers: K hi/lo x2 rows, Vt hi/lo x2 rows
    u16x8 p0, p1, p2, p3, p4, p5, p6, p7;
    {
        const size_t kb = bh + (size_t)srow * DH + sch;
        p0 = *(const u16x8*)&kh_g[kb];
        p1 = *(const u16x8*)&kh_g[kb + 32 * DH];
        p2 = *(const u16x8*)&kl_g[kb];
        p3 = *(const u16x8*)&kl_g[kb + 32 * DH];
        const size_t vb_ = bh + (size_t)srow * SEQ + sch;
        p4 = *(const u16x8*)&vh_g[vb_];
        p5 = *(const u16x8*)&vh_g[vb_ + 32 * SEQ];
        p6 = *(const u16x8*)&vl_g[vb_];
        p7 = *(const u16x8*)&vl_g[vb_ + 32 * SEQ];
    }

    for (int jt = 0; jt < 8; ++jt) {
        const int j0 = jt << 6;
        const int base = j0 - i0 + 448;
        __syncthreads();                 // K/V buffers free
        *(u16x8*)&Kh[srow][sch] = p0;
        *(u16x8*)&Kh[srow + 32][sch] = p1;
        *(u16x8*)&Kl[srow][sch] = p2;
        *(u16x8*)&Kl[srow + 32][sch] = p3;
        *(u16x8*)&Vh[srow][sch] = p4;
        *(u16x8*)&Vh[srow + 32][sch] = p5;
        *(u16x8*)&Vl[srow][sch] = p6;
        *(u16x8*)&Vl[srow + 32][sch] = p7;
        __syncthreads();                 // K/V buffers ready
        if (jt < 7) {                    // issue next tile's loads NOW
            const int jn = j0 + 64;
            const size_t kb = bh + (size_t)(jn + srow) * DH + sch;
            p0 = *(const u16x8*)&kh_g[kb];
            p1 = *(const u16x8*)&kh_g[kb + 32 * DH];
            p2 = *(const u16x8*)&kl_g[kb];
            p3 = *(const u16x8*)&kl_g[kb + 32 * DH];
            const size_t vb_ = bh + (size_t)srow * SEQ + jn + sch;
            p4 = *(const u16x8*)&vh_g[vb_];
            p5 = *(const u16x8*)&vh_g[vb_ + 32 * SEQ];
            p6 = *(const u16x8*)&vl_g[vb_];
            p7 = *(const u16x8*)&vl_g[vb_ + 32 * SEQ];
        }

        // content scores from LDS K
        __builtin_amdgcn_s_setprio(1);
        f32x4 accs[4];
#pragma unroll
        for (int nf = 0; nf < 4; ++nf) accs[nf] = (f32x4){0.f, 0.f, 0.f, 0.f};
#pragma unroll
        for (int ks = 0; ks < 2; ++ks)
#pragma unroll
            for (int nf = 0; nf < 4; ++nf) {
                bf16x8 b_h = *(const bf16x8*)&Kh[(nf << 4) + c][(ks << 5) + (g << 3)];
                bf16x8 b_l = *(const bf16x8*)&Kl[(nf << 4) + c][(ks << 5) + (g << 3)];
                accs[nf] = mfma16(qhf[ks], b_h, accs[nf]);
                accs[nf] = mfma16(qhf[ks], b_l, accs[nf]);
                accs[nf] = mfma16(qlf[ks], b_h, accs[nf]);
            }

        // position dd-GEMM: Pdd[i][ddl] = qu[i].R[base_g+ddl] + rc
        const int base_g = j0 - R0 + 496;
#pragma unroll
        for (int f = 0; f < 5; ++f) {
            f32x4 ap = (f32x4){0.f, 0.f, 0.f, 0.f};
#pragma unroll
            for (int ks = 0; ks < 2; ++ks) {
                const size_t ro = (size_t)(base_g + (f << 4) + c) * DH
                                + (ks << 5) + (g << 3);
                bf16x8 b_h = *(const bf16x8*)&rmhh[ro];
                bf16x8 b_l = *(const bf16x8*)&rmlh[ro];
                ap = mfma16(qhf[ks], b_h, ap);
                ap = mfma16(qhf[ks], b_l, ap);
                ap = mfma16(qlf[ks], b_h, ap);
            }
            const float rcv = rch[base_g + (f << 4) + c];
#pragma unroll
            for (int r = 0; r < 4; ++r)
                Pdd[wid][(g << 2) + r][(f << 4) + c] = f2bf(ap[r] + rcv);
        }
        __builtin_amdgcn_s_setprio(0);

        // online softmax per row (gather Pdd at ddl = j - i + 15)
#pragma unroll
        for (int r = 0; r < 4; ++r) {
            const int irow = (g << 2) + r;
            float sc[4];
#pragma unroll
            for (int nf = 0; nf < 4; ++nf) {
                const int ddl = (nf << 4) + c - irow + 15;
                sc[nf] = (accs[nf][r] + bf2f(Pdd[wid][irow][ddl])) * 0.125f;
            }
            float mt = fmaxf(fmaxf(sc[0], sc[1]), fmaxf(sc[2], sc[3]));
#pragma unroll
            for (int off = 8; off; off >>= 1) mt = fmaxf(mt, __shfl_xor(mt, off, 16));
            const float mn = fmaxf(m_r[r], mt);
            const float alpha = __expf(m_r[r] - mn);
            m_r[r] = mn;
            float rs = 0.f;
#pragma unroll
            for (int nf = 0; nf < 4; ++nf) {
                const float p = __expf(sc[nf] - mn);
                Pt[wid][irow][(nf << 4) + c] = p;
                rs += p;
            }
#pragma unroll
            for (int off = 8; off; off >>= 1) rs += __shfl_xor(rs, off, 16);
            l_r[r] = l_r[r] * alpha + rs;
#pragma unroll
            for (int nf = 0; nf < 4; ++nf) Oacc[nf][r] *= alpha;
        }

        // PV: A = P (hi/lo from Pt), B = Vt from LDS
        __builtin_amdgcn_s_setprio(1);
#pragma unroll
        for (int ks = 0; ks < 2; ++ks) {
            f4 pv0 = *(const f4*)&Pt[wid][c][(ks << 5) + (g << 3)];
            f4 pv1 = *(const f4*)&Pt[wid][c][(ks << 5) + (g << 3) + 4];
            float pv[8] = {pv0.x, pv0.y, pv0.z, pv0.w, pv1.x, pv1.y, pv1.z, pv1.w};
            bf16x8 ph, pl;
#pragma unroll
            for (int e = 0; e < 8; ++e) {
                const unsigned short hb = f2bf(pv[e]);
                ph[e] = (short)hb;
                pl[e] = (short)f2bf(pv[e] - bf2f(hb));
            }
#pragma unroll
            for (int nf = 0; nf < 4; ++nf) {
                bf16x8 v_h = *(const bf16x8*)&Vh[(nf << 4) + c][(ks << 5) + (g << 3)];
                bf16x8 v_l = *(const bf16x8*)&Vl[(nf << 4) + c][(ks << 5) + (g << 3)];
                Oacc[nf] = mfma16(ph, v_h, Oacc[nf]);
                Oacc[nf] = mfma16(ph, v_l, Oacc[nf]);
                Oacc[nf] = mfma16(pl, v_h, Oacc[nf]);
            }
        }
        __builtin_amdgcn_s_setprio(0);
    }

    // epilogue: normalize, split hi/lo, store ctx[b][s][h*64+d]
    float inv[4];
#pragma unroll
    for (int r = 0; r < 4; ++r) inv[r] = 1.f / l_r[r];
#pragma unroll
    for (int nf = 0; nf < 4; ++nf)
#pragma unroll
        for (int r = 0; r < 4; ++r) {
            const float val = Oacc[nf][r] * inv[r];
            const int s = R0 + (g << 2) + r;
            const int d = (h << 6) + (nf << 4) + c;
            const size_t o = ((size_t)(b * SEQ) + s) * DM + d;
            const unsigned short hb = f2bf(val);
            cth[o] = hb;
            ctl[o] = f2bf(val - bf2f(hb));
        }
}

extern "C" void kernel_launch(void* const* d_in, const int* in_sizes, int n_in,
                              void* d_out, int out_size, void* d_ws, size_t ws_size,
                              hipStream_t stream)
{
    const float* x  = (const float*)d_in[0];
    const float* wq = (const float*)d_in[1];
    const float* bq = (const float*)d_in[2];
    const float* wk = (const float*)d_in[3];
    const float* bk = (const float*)d_in[4];
    const float* wv = (const float*)d_in[5];
    const float* bv = (const float*)d_in[6];
    const float* wo = (const float*)d_in[7];
    const float* bo = (const float*)d_in[8];
    const float* wr = (const float*)d_in[9];
    const float* u  = (const float*)d_in[10];
    const float* vb = (const float*)d_in[11];
    const float* pe = (const float*)d_in[12];
    float* out = (float*)d_out;
    unsigned short* us = (unsigned short*)d_ws;

    unsigned short* xh  = us;                    // 2097152
    unsigned short* xl  = us + 2097152;
    unsigned short* wb  = us + 4194304;          // 5 x (hi 262144 + lo 262144)
    unsigned short* peh = us + 6815744;          // 524288
    unsigned short* pel = us + 7340032;
    unsigned short* qh  = us + 7864320;          // 2097152 each
    unsigned short* ql  = us + 9961472;
    unsigned short* kh  = us + 12058624;
    unsigned short* kl  = us + 14155776;
    unsigned short* vth = us + 16252928;
    unsigned short* vtl = us + 18350080;
    unsigned short* rmh = us + 20447232;         // 524288 each
    unsigned short* rml = us + 20971520;
    unsigned short* cth = us + 21495808;
    unsigned short* ctl = us + 23592960;
    float* rc = (float*)(us + 25690112);         // 8192 f32

    unsigned short* woh = wb + 3 * 524288;
    unsigned short* wol = woh + 262144;
    unsigned short* wrh = wb + 4 * 524288;
    unsigned short* wrl = wrh + 262144;

    dim3 blk(256);
    cvt_kernel<<<1024, blk, 0, stream>>>(x, xh, xl, 2097152);
    cvt_w_kernel<<<dim3(128, 5), blk, 0, stream>>>(wq, wk, wv, wo, wr, wb);
    cvt_kernel<<<256, blk, 0, stream>>>(pe + (size_t)PE_OFF * DM, peh, pel, 523776);

    qkv_kernel<<<dim3(24, 64), blk, 0, stream>>>(xh, xl, wb, bq, bk, bv, u,
                                                 qh, ql, kh, kl, vth, vtl);
    rm_kernel<<<dim3(8, 16), blk, 0, stream>>>(peh, pel, wrh, wrl, rmh, rml);
    corr_kernel<<<dim3(16, 8), dim3(64), 0, stream>>>(rmh, rml, u, vb, rc);
    attn_kernel<<<dim3(8, 8, 8), blk, 0, stream>>>(qh, ql, kh, kl, vth, vtl,
                                                   rmh, rml, rc, cth, ctl);
    out_kernel<<<dim3(8, 64), blk, 0, stream>>>(cth, ctl, woh, wol, bo, out);
}